// Round 9
// baseline (115.456 us; speedup 1.0000x reference)
//
#include <hip/hip_runtime.h>
#include <stdint.h>

#define N_SEQ 2048
#define QKFV_COLS 2048

typedef __attribute__((ext_vector_type(8))) __bf16 bf16x8;
typedef __attribute__((ext_vector_type(4))) __bf16 bf16x4;
typedef __attribute__((ext_vector_type(4))) float f32x4;
typedef __attribute__((ext_vector_type(16))) float f32x16;

#if __has_builtin(__builtin_amdgcn_exp2f)
#define EXP2(x) __builtin_amdgcn_exp2f(x)
#else
#define EXP2(x) exp2f(x)
#endif

__device__ __forceinline__ f32x4 mfma16(bf16x8 a, bf16x8 b, f32x4 c) {
  return __builtin_amdgcn_mfma_f32_16x16x32_bf16(a, b, c, 0, 0, 0);
}
__device__ __forceinline__ f32x16 mfma32(bf16x8 a, bf16x8 b, f32x16 c) {
  return __builtin_amdgcn_mfma_f32_32x32x16_bf16(a, b, c, 0, 0, 0);
}

__device__ __forceinline__ void glds16(const void* g, void* l) {
  __builtin_amdgcn_global_load_lds(
      (__attribute__((address_space(1))) uint32_t*)(uintptr_t)g,
      (__attribute__((address_space(3))) uint32_t*)l, 16, 0, 0);
}

// ---------------- fused prep: cast x + 3 LDS-tiled transposes ----------------
__global__ __launch_bounds__(256) void prep_kernel(const float* __restrict__ x,
                                                   __bf16* __restrict__ xbf,
                                                   const float* __restrict__ wqk,
                                                   __bf16* __restrict__ wqT,
                                                   const float* __restrict__ wo,
                                                   __bf16* __restrict__ woT,
                                                   const float* __restrict__ wsc,
                                                   __bf16* __restrict__ wscT) {
  const int t = threadIdx.x;
  int bid = blockIdx.x;
  if (bid < 2048) {
    size_t i = (size_t)bid * 2048 + t * 8;
    const float* p = x + i;
    bf16x8 o;
#pragma unroll
    for (int j = 0; j < 8; ++j) o[j] = (__bf16)p[j];
    *(bf16x8*)(xbf + i) = o;
    return;
  }
  bid -= 2048;
  const float* in;
  __bf16* outp;
  int R, C, rt, ct;
  if (bid < 256) { in = wqk; outp = wqT; R = 512; C = 2048; rt = bid >> 5; ct = bid & 31; }
  else if (bid < 320) { int b2 = bid - 256; in = wo; outp = woT; R = 512; C = 512; rt = b2 >> 3; ct = b2 & 7; }
  else { int b2 = bid - 320; in = wsc; outp = wscT; R = 64; C = 2048; rt = 0; ct = b2; }
  __shared__ __bf16 tile[64][72];
  const int r0 = rt * 64, c0 = ct * 64;
  {
    const int r = t >> 2, cq = (t & 3) * 16;
    const float* src = in + (size_t)(r0 + r) * C + c0 + cq;
#pragma unroll
    for (int q = 0; q < 4; ++q) {
      f32x4 v = *(const f32x4*)(src + q * 4);
#pragma unroll
      for (int e = 0; e < 4; ++e) tile[r][cq + q * 4 + e] = (__bf16)v[e];
    }
  }
  __syncthreads();
  {
    const int c = t >> 2, rq = (t & 3) * 16;
    __bf16* dst = outp + (size_t)(c0 + c) * R + r0 + rq;
    bf16x8 o0, o1;
#pragma unroll
    for (int j = 0; j < 8; ++j) { o0[j] = tile[rq + j][c]; o1[j] = tile[rq + 8 + j][c]; }
    *(bf16x8*)dst = o0;
    *(bf16x8*)(dst + 8) = o1;
  }
}

// ---------------- gemm_qkfv: BM128 x BN256 x BK32, 8 waves, 2 blocks/CU ----------------
__global__ __launch_bounds__(512, 4) void gemm_qkfv_kernel(const __bf16* __restrict__ A,
                                                           const __bf16* __restrict__ Bt,
                                                           __bf16* __restrict__ C,
                                                           __bf16* __restrict__ fT,
                                                           __bf16* __restrict__ vT) {
  __shared__ alignas(16) __bf16 Ab[2][128 * 32];
  __shared__ alignas(16) __bf16 Bb[2][256 * 32];
  const int K = 512, N = 2048;
  const int t = threadIdx.x;
  const int w = t >> 6;
  const int lane = t & 63;
  const int l15 = lane & 15;
  const int q4 = lane >> 4;
  const int g4 = q4 * 4;
  const int wr = w >> 2, wc = w & 3;
  const int bid = blockIdx.x;
  const int n0 = (bid & 7) * 256;
  const int m0 = (bid >> 3) * 128;

  const __bf16* srcA;
  const __bf16* srcB[2];
  {
    int s = t, r = s >> 2, u = (s & 3) ^ (r & 3);
    srcA = A + (size_t)(m0 + r) * K + u * 8;
  }
#pragma unroll
  for (int c = 0; c < 2; ++c) {
    int s = c * 512 + t, r = s >> 2, u = (s & 3) ^ (r & 3);
    srcB[c] = Bt + (size_t)(n0 + r) * K + u * 8;
  }

  f32x4 acc[4][4];
#pragma unroll
  for (int m = 0; m < 4; ++m)
#pragma unroll
    for (int n = 0; n < 4; ++n) acc[m][n] = (f32x4){0.f, 0.f, 0.f, 0.f};

  glds16(srcA, &Ab[0][t * 8]);
  glds16(srcB[0], &Bb[0][t * 8]);
  glds16(srcB[1], &Bb[0][(512 + t) * 8]);

  for (int kt = 0; kt < 16; ++kt) {
    const int cur = kt & 1;
    asm volatile("s_waitcnt vmcnt(0)" ::: "memory");
    __builtin_amdgcn_s_barrier();
    if (kt < 15) {
      const int k0 = (kt + 1) * 32;
      glds16(srcA + k0, &Ab[cur ^ 1][t * 8]);
      glds16(srcB[0] + k0, &Bb[cur ^ 1][t * 8]);
      glds16(srcB[1] + k0, &Bb[cur ^ 1][(512 + t) * 8]);
    }
    bf16x8 af[4], bf[4];
#pragma unroll
    for (int m = 0; m < 4; ++m) {
      const int R = wr * 64 + m * 16 + l15;
      af[m] = *(const bf16x8*)&Ab[cur][R * 32 + ((q4 ^ (R & 3)) * 8)];
    }
#pragma unroll
    for (int n = 0; n < 4; ++n) {
      const int R = wc * 64 + n * 16 + l15;
      bf[n] = *(const bf16x8*)&Bb[cur][R * 32 + ((q4 ^ (R & 3)) * 8)];
    }
    __builtin_amdgcn_s_setprio(1);
#pragma unroll
    for (int m = 0; m < 4; ++m)
#pragma unroll
      for (int n = 0; n < 4; ++n) acc[m][n] = mfma16(af[m], bf[n], acc[m][n]);
    __builtin_amdgcn_s_setprio(0);
    __builtin_amdgcn_s_barrier();
  }

  if (n0 < 1024) {
#pragma unroll
    for (int m = 0; m < 4; ++m)
#pragma unroll
      for (int n = 0; n < 4; ++n) {
        const int col = n0 + wc * 64 + n * 16 + l15;
        const int row = m0 + wr * 64 + m * 16 + g4;
#pragma unroll
        for (int r = 0; r < 4; ++r)
          C[(size_t)(row + r) * N + col] = (__bf16)acc[m][n][r];
      }
  } else {
    __bf16* T = (n0 < 1536) ? fT : vT;
    const int cbase = (n0 < 1536) ? 1024 : 1536;
#pragma unroll
    for (int m = 0; m < 4; ++m)
#pragma unroll
      for (int n = 0; n < 4; ++n) {
        const int hc = n0 + wc * 64 + n * 16 + l15 - cbase;  // 0..511
        const int h = hc >> 6, d = hc & 63;
        const int row = m0 + wr * 64 + m * 16 + g4;
        const int b = row >> 11, nl = row & 2047;
        bf16x4 pk;
#pragma unroll
        for (int r = 0; r < 4; ++r) pk[r] = (__bf16)acc[m][n][r];
        *(bf16x4*)&T[(size_t)((b * 8 + h) * 64 + d) * 2048 + nl] = pk;
      }
  }
}

// ---------------- gemm_out: BM128 x BN64 x BK32, 8 waves, grid 512 ----------------
__global__ __launch_bounds__(512, 4) void gemm_out_kernel(const __bf16* __restrict__ A,
                                                          const __bf16* __restrict__ Bt,
                                                          float* __restrict__ out,
                                                          const float* __restrict__ bias) {
  __shared__ alignas(16) __bf16 As[128 * 32];
  __shared__ alignas(16) __bf16 Bs[64 * 32];
  const int K = 512, N = 512;
  const int t = threadIdx.x;
  const int w = t >> 6;
  const int lane = t & 63;
  const int l15 = lane & 15;
  const int q4 = lane >> 4;
  const int g4 = q4 * 4;
  const int wr = w >> 1, wc = w & 1;
  const int m0 = blockIdx.x * 128, n0 = blockIdx.y * 64;

  const __bf16* srcA;
  const __bf16* srcB;
  {
    int s = t, r = s >> 2, u = (s & 3) ^ (r & 3);
    srcA = A + (size_t)(m0 + r) * K + u * 8;
    srcB = Bt + (size_t)(n0 + (r & 63)) * K + u * 8;
  }

  f32x4 acc[2][2];
#pragma unroll
  for (int m = 0; m < 2; ++m)
#pragma unroll
    for (int n = 0; n < 2; ++n) acc[m][n] = (f32x4){0.f, 0.f, 0.f, 0.f};

  for (int kt = 0; kt < 16; ++kt) {
    const int k0 = kt * 32;
    glds16(srcA + k0, &As[t * 8]);
    if (t < 256) glds16(srcB + k0, &Bs[t * 8]);
    __syncthreads();
    bf16x8 af[2], bf[2];
#pragma unroll
    for (int m = 0; m < 2; ++m) {
      const int R = wr * 32 + m * 16 + l15;
      af[m] = *(const bf16x8*)&As[R * 32 + ((q4 ^ (R & 3)) * 8)];
    }
#pragma unroll
    for (int n = 0; n < 2; ++n) {
      const int R = wc * 32 + n * 16 + l15;
      bf[n] = *(const bf16x8*)&Bs[R * 32 + ((q4 ^ (R & 3)) * 8)];
    }
#pragma unroll
    for (int m = 0; m < 2; ++m)
#pragma unroll
      for (int n = 0; n < 2; ++n) acc[m][n] = mfma16(af[m], bf[n], acc[m][n]);
    __syncthreads();
  }

#pragma unroll
  for (int m = 0; m < 2; ++m)
#pragma unroll
    for (int n = 0; n < 2; ++n) {
      const int col = n0 + wc * 32 + n * 16 + l15;
      const float bv = bias[col];
      const int row = m0 + wr * 32 + m * 16 + g4;
#pragma unroll
      for (int r = 0; r < 4; ++r)
        out[(size_t)(row + r) * N + col] = acc[m][n][r] + bv;
    }
}

// ---------------- fvmm ----------------
__global__ __launch_bounds__(256) void fvmm_kernel(const __bf16* __restrict__ fT,
                                                   const __bf16* __restrict__ vT,
                                                   float* __restrict__ fvp) {
  __shared__ alignas(16) __bf16 As[2 * 8192];
  __shared__ alignas(16) __bf16 Bs[2 * 8192];
  const int t = threadIdx.x;
  const int w = t >> 6;
  const int lane = t & 63;
  const int l15 = lane & 15;
  const int q4 = lane >> 4;
  const int g4 = q4 * 4;
  const int sl = blockIdx.x;
  const int bh = blockIdx.y;
  const int k0 = sl * 256;
  const __bf16* A = fT + (size_t)bh * 131072 + k0;
  const __bf16* B = vT + (size_t)bh * 131072 + k0;

#pragma unroll
  for (int kt = 0; kt < 2; ++kt)
#pragma unroll
    for (int c = 0; c < 4; ++c) {
      int slot = c * 256 + t;
      int r = slot >> 4, u = (slot & 15) ^ (r & 7);
      glds16(A + (size_t)r * 2048 + kt * 128 + u * 8, &As[kt * 8192 + (c * 256 + w * 64) * 8]);
      glds16(B + (size_t)r * 2048 + kt * 128 + u * 8, &Bs[kt * 8192 + (c * 256 + w * 64) * 8]);
    }
  asm volatile("s_waitcnt vmcnt(0)" ::: "memory");
  __syncthreads();

  f32x4 acc[4];
#pragma unroll
  for (int nb = 0; nb < 4; ++nb) acc[nb] = (f32x4){0.f, 0.f, 0.f, 0.f};
  const int arow = w * 16 + l15;
#pragma unroll
  for (int ks = 0; ks < 8; ++ks) {
    const int kt = ks >> 2;
    const int ku = (ks & 3) * 4 + q4;
    bf16x8 a = *(const bf16x8*)&As[kt * 8192 + arow * 128 + ((ku ^ (arow & 7)) * 8)];
#pragma unroll
    for (int nb = 0; nb < 4; ++nb) {
      const int br = nb * 16 + l15;
      bf16x8 bb = *(const bf16x8*)&Bs[kt * 8192 + br * 128 + ((ku ^ (br & 7)) * 8)];
      acc[nb] = mfma16(a, bb, acc[nb]);
    }
  }
  float* dst = fvp + (size_t)(sl * 32 + bh) * 4096;
#pragma unroll
  for (int nb = 0; nb < 4; ++nb)
#pragma unroll
    for (int r = 0; r < 4; ++r)
      dst[(w * 16 + g4 + r) * 64 + nb * 16 + l15] = acc[nb][r];
}

// ---------------- pvmat2 ----------------
__global__ __launch_bounds__(256) void pvmat2_kernel(const float* __restrict__ fvp,
                                                     const __bf16* __restrict__ wscT,
                                                     const float* __restrict__ bsc,
                                                     __bf16* __restrict__ pvm) {
  __shared__ alignas(16) __bf16 fs[64 * 72];
  __shared__ alignas(16) __bf16 Ws[128 * 64];
  const int t = threadIdx.x;
  const int w = t >> 6;
  const int lane = t & 63;
  const int l15 = lane & 15;
  const int q4 = lane >> 4;
  const int g4 = q4 * 4;
  const int bh = blockIdx.y;
  const int j0 = blockIdx.x * 128;

#pragma unroll
  for (int c = 0; c < 4; ++c) {
    int slot = c * 256 + t;
    int r = slot >> 3, u = (slot & 7) ^ (r & 7);
    glds16(wscT + (size_t)(j0 + r) * 64 + u * 8, &Ws[(c * 256 + w * 64) * 8]);
  }
#pragma unroll
  for (int qq = 0; qq < 4; ++qq) {
    int idx = t * 16 + qq * 4;
    f32x4 s = (f32x4){0.f, 0.f, 0.f, 0.f};
#pragma unroll
    for (int sl = 0; sl < 8; ++sl)
      s += *(const f32x4*)&fvp[(size_t)(sl * 32 + bh) * 4096 + idx];
    bf16x4 pk;
#pragma unroll
    for (int e = 0; e < 4; ++e) pk[e] = (__bf16)s[e];
    *(bf16x4*)&fs[(idx >> 6) * 72 + (idx & 63)] = pk;
  }
  asm volatile("s_waitcnt vmcnt(0)" ::: "memory");
  __syncthreads();

  f32x4 acc[8];
#pragma unroll
  for (int nb = 0; nb < 8; ++nb) {
    float bv = bsc[j0 + nb * 16 + l15];
    acc[nb] = (f32x4){bv, bv, bv, bv};
  }
  const int arow = w * 16 + l15;
#pragma unroll
  for (int ks = 0; ks < 2; ++ks) {
    bf16x8 a = *(const bf16x8*)&fs[arow * 72 + ks * 32 + q4 * 8];
#pragma unroll
    for (int nb = 0; nb < 8; ++nb) {
      const int jr = nb * 16 + l15;
      bf16x8 bb = *(const bf16x8*)&Ws[jr * 64 + (((ks * 4 + q4) ^ (jr & 7)) * 8)];
      acc[nb] = mfma16(a, bb, acc[nb]);
    }
  }
  __bf16* dst = pvm + (size_t)bh * 131072 + (size_t)j0;
#pragma unroll
  for (int nb = 0; nb < 8; ++nb)
#pragma unroll
    for (int r = 0; r < 4; ++r)
      dst[(size_t)(w * 16 + g4 + r) * 2048 + nb * 16 + l15] = (__bf16)acc[nb][r];
}

// ---------------- flash attention: 4-wave, 2 i-subblocks/wave, j-split ----------------
// 256 threads = 2 j-groups x 2 waves; each wave owns 64 i-rows (2 subblocks of 32).
// Each K/V LDS fragment read now feeds 2 MFMAs (was 1) -> LDS read traffic halves.
// K frags held in regs across both QK phases; V frag read once per kk feeds 4 MFMAs.
__global__ __launch_bounds__(256, 2) void attn_kernel(const __bf16* __restrict__ qkfv,
                                                      const __bf16* __restrict__ pvm,
                                                      __bf16* __restrict__ obuf) {
  __shared__ alignas(16) char smem[65536];
  __bf16* Kb = (__bf16*)smem;             // [4][4096] : (g*2+buf)*4096
  __bf16* Vb = (__bf16*)(smem + 32768);   // [4][4096]
  const int t = threadIdx.x;
  const int w = t >> 6;        // 0..3
  const int g = w >> 1;        // j-group
  const int wq = w & 1;
  const int lane = t & 63;
  const int ln = lane & 31;
  const int hi = lane >> 5;
  const int p = blockIdx.x;
  const int bh = (p & 7) * 4 + ((p >> 3) & 3);
  const int iblk = p >> 5;     // 0..15
  const int b = bh >> 3, h = bh & 7;
  const float K1 = 0.18033688f;  // 0.125 * log2(e), folded into Q
  const int swz = ln & 7;

  // Q fragments for 2 i-subblocks, pre-scaled by K1
  bf16x8 qa[4], qb[4];
  {
    const __bf16* qr = qkfv + (size_t)(b * N_SEQ + iblk * 128 + wq * 64 + ln) * QKFV_COLS + h * 64 + hi * 8;
#pragma unroll
    for (int kf = 0; kf < 4; ++kf) {
      bf16x8 r0 = *(const bf16x8*)(qr + kf * 16);
      bf16x8 r1 = *(const bf16x8*)(qr + 32 * QKFV_COLS + kf * 16);
#pragma unroll
      for (int e = 0; e < 8; ++e) {
        qa[kf][e] = (__bf16)((float)r0[e] * K1);
        qb[kf][e] = (__bf16)((float)r1[e] * K1);
      }
    }
  }

  // staging sources: group g staged by its 128 threads (tg), 4 chunks K + 4 V
  const int tg = t & 127;
  const __bf16* ksrc[4];
  const __bf16* vsrc[4];
#pragma unroll
  for (int it = 0; it < 4; ++it) {
    int s = it * 128 + tg;
    int r = s >> 3;
    int u = (s & 7) ^ (r & 7);
    ksrc[it] = qkfv + (size_t)(b * N_SEQ + g * 1024 + r) * QKFV_COLS + 512 + h * 64 + u * 8;
    vsrc[it] = pvm + ((size_t)bh * 64 + r) * 2048 + g * 1024 + u * 8;
  }

  auto stage = [&](int buf, int jt) {
#pragma unroll
    for (int it = 0; it < 4; ++it) {
      glds16(ksrc[it] + ((size_t)jt << 17), &Kb[(g * 2 + buf) * 4096 + (it * 128 + tg) * 8]);
      glds16(vsrc[it] + jt * 64, &Vb[(g * 2 + buf) * 4096 + (it * 128 + tg) * 8]);
    }
  };

  f32x16 o00, o01, o10, o11;
#pragma unroll
  for (int e = 0; e < 16; ++e) { o00[e] = 0.f; o01[e] = 0.f; o10[e] = 0.f; o11[e] = 0.f; }
  float lr0 = 0.f, lr1 = 0.f;

  stage(0, 0);

  for (int jt = 0; jt < 16; ++jt) {
    asm volatile("s_waitcnt vmcnt(0)" ::: "memory");
    __builtin_amdgcn_s_barrier();
    if (jt < 15) stage((jt & 1) ^ 1, jt + 1);
    const int kc = (g * 2 + (jt & 1)) * 4096;

    // K fragments once, reused for both subblocks
    bf16x8 k0f[4], k1f[4];
#pragma unroll
    for (int kf = 0; kf < 4; ++kf) {
      k0f[kf] = *(const bf16x8*)&Kb[kc + (ln) * 64 + (((2 * kf + hi) ^ swz) * 8)];
      k1f[kf] = *(const bf16x8*)&Kb[kc + (32 + ln) * 64 + (((2 * kf + hi) ^ swz) * 8)];
    }

    bf16x8 pa0[4], pa1[4];
#pragma unroll
    for (int sb = 0; sb < 2; ++sb) {
      f32x16 s0, s1;
#pragma unroll
      for (int e = 0; e < 16; ++e) { s0[e] = 0.f; s1[e] = 0.f; }
      __builtin_amdgcn_s_setprio(1);
#pragma unroll
      for (int kf = 0; kf < 4; ++kf) {
        bf16x8 qf = sb == 0 ? qa[kf] : qb[kf];
        s0 = mfma32(k0f[kf], qf, s0);
        s1 = mfma32(k1f[kf], qf, s1);
      }
      __builtin_amdgcn_s_setprio(0);

#pragma unroll
      for (int e = 0; e < 16; ++e) s0[e] = EXP2(s0[e]);
#pragma unroll
      for (int e = 0; e < 16; ++e) s1[e] = EXP2(s1[e]);
      float a8[8];
#pragma unroll
      for (int e = 0; e < 8; ++e)
        a8[e] = (s0[e] + s0[e + 8]) + (s1[e] + s1[e + 8]);
      float ls = ((a8[0] + a8[4]) + (a8[1] + a8[5])) + ((a8[2] + a8[6]) + (a8[3] + a8[7]));
      if (sb == 0) lr0 += ls; else lr1 += ls;

#pragma unroll
      for (int kk = 0; kk < 4; ++kk) {
        const f32x16& sf = (kk < 2) ? s0 : s1;
        const int rb = (kk & 1) * 8;
        uint32_t a0, a1, b0, b1;
        asm("v_cvt_pk_bf16_f32 %0, %1, %2" : "=v"(a0) : "v"(sf[rb + 0]), "v"(sf[rb + 1]));
        asm("v_cvt_pk_bf16_f32 %0, %1, %2" : "=v"(a1) : "v"(sf[rb + 2]), "v"(sf[rb + 3]));
        asm("v_cvt_pk_bf16_f32 %0, %1, %2" : "=v"(b0) : "v"(sf[rb + 4]), "v"(sf[rb + 5]));
        asm("v_cvt_pk_bf16_f32 %0, %1, %2" : "=v"(b1) : "v"(sf[rb + 6]), "v"(sf[rb + 7]));
        asm("v_permlane32_swap_b32 %0, %1" : "+v"(a0), "+v"(b0));
        asm("v_permlane32_swap_b32 %0, %1" : "+v"(a1), "+v"(b1));
        union { uint32_t u[4]; bf16x8 v; } cv;
        cv.u[0] = a0; cv.u[1] = a1; cv.u[2] = b0; cv.u[3] = b1;
        if (sb == 0) pa0[kk] = cv.v; else pa1[kk] = cv.v;
      }
    }

    // PV: each V fragment feeds 4 MFMAs (2 subblocks x 2 d-halves)
    __builtin_amdgcn_s_setprio(1);
#pragma unroll
    for (int kk = 0; kk < 4; ++kk) {
      bf16x8 v0 = *(const bf16x8*)&Vb[kc + (ln) * 64 + (((2 * kk + hi) ^ swz) * 8)];
      bf16x8 v1 = *(const bf16x8*)&Vb[kc + (32 + ln) * 64 + (((2 * kk + hi) ^ swz) * 8)];
      o00 = mfma32(v0, pa0[kk], o00);
      o01 = mfma32(v1, pa0[kk], o01);
      o10 = mfma32(v0, pa1[kk], o10);
      o11 = mfma32(v1, pa1[kk], o11);
    }
    __builtin_amdgcn_s_setprio(0);
  }

  lr0 += __shfl_xor(lr0, 32);
  lr1 += __shfl_xor(lr1, 32);

  // in-block j-merge: group 1 (w>=2) dumps, group 0 (w<2) merges+writes
  __syncthreads();
  float* Om = (float*)smem;  // [2][64][67]
  if (w >= 2) {
    const int base = ((w - 2) * 64 + lane) * 67;
#pragma unroll
    for (int e = 0; e < 16; ++e) {
      Om[base + e] = o00[e];
      Om[base + 16 + e] = o01[e];
      Om[base + 32 + e] = o10[e];
      Om[base + 48 + e] = o11[e];
    }
    Om[base + 64] = lr0;
    Om[base + 65] = lr1;
  }
  __syncthreads();
  if (w < 2) {
    const int base = (w * 64 + lane) * 67;
#pragma unroll
    for (int e = 0; e < 16; ++e) {
      o00[e] += Om[base + e];
      o01[e] += Om[base + 16 + e];
      o10[e] += Om[base + 32 + e];
      o11[e] += Om[base + 48 + e];
    }
    lr0 += Om[base + 64];
    lr1 += Om[base + 65];

    const float inv0 = 1.0f / lr0;
    const float inv1 = 1.0f / lr1;
#pragma unroll
    for (int sb = 0; sb < 2; ++sb) {
      const float inv = sb == 0 ? inv0 : inv1;
      const size_t orow = (size_t)(b * N_SEQ + iblk * 128 + wq * 64 + sb * 32 + ln) * 512 + h * 64;
#pragma unroll
      for (int df = 0; df < 2; ++df) {
        const f32x16& oo = sb == 0 ? (df ? o01 : o00) : (df ? o11 : o10);
#pragma unroll
        for (int gg = 0; gg < 4; ++gg) {
          bf16x4 pk;
#pragma unroll
          for (int e = 0; e < 4; ++e) pk[e] = (__bf16)(oo[gg * 4 + e] * inv);
          *(bf16x4*)(obuf + orow + df * 32 + gg * 8 + hi * 4) = pk;
        }
      }
    }
  }
}

extern "C" void kernel_launch(void* const* d_in, const int* in_sizes, int n_in,
                              void* d_out, int out_size, void* d_ws, size_t ws_size,
                              hipStream_t stream) {
  (void)in_sizes; (void)n_in; (void)out_size; (void)ws_size;
  const float* x   = (const float*)d_in[0];
  const float* wqk = (const float*)d_in[1];
  const float* wsc = (const float*)d_in[2];
  const float* bsc = (const float*)d_in[3];
  const float* wo  = (const float*)d_in[4];
  const float* bo  = (const float*)d_in[5];
  float* out = (float*)d_out;

  char* p = (char*)d_ws;
  __bf16* xbf  = (__bf16*)p;  p += (size_t)8192 * 512 * 2;   // dead after gemm_qkfv -> fvp
  __bf16* wqT  = (__bf16*)p;  p += (size_t)2048 * 512 * 2;
  __bf16* woT  = (__bf16*)p;  p += (size_t)512 * 512 * 2;
  __bf16* wscT = (__bf16*)p;  p += (size_t)2048 * 64 * 2;
  __bf16* qkfv = (__bf16*)p;  p += (size_t)8192 * 2048 * 2;  // only q/k halves used
  __bf16* pvm  = (__bf16*)p;  p += (size_t)32 * 64 * 2048 * 2;  // doubles as vT
  __bf16* obuf = (__bf16*)p;  p += (size_t)8192 * 512 * 2;      // doubles as fT
  float* fvp = (float*)xbf;
  __bf16* fT = obuf;
  __bf16* vT = pvm;

  prep_kernel<<<dim3(2400), dim3(256), 0, stream>>>(x, xbf, wqk, wqT, wo, woT, wsc, wscT);
  gemm_qkfv_kernel<<<dim3(512), dim3(512), 0, stream>>>(xbf, wqT, qkfv, fT, vT);
  fvmm_kernel<<<dim3(8, 32), dim3(256), 0, stream>>>(fT, vT, fvp);
  pvmat2_kernel<<<dim3(16, 32), dim3(256), 0, stream>>>(fvp, wscT, bsc, pvm);
  attn_kernel<<<dim3(512), dim3(256), 0, stream>>>(qkfv, pvm, obuf);
  gemm_out_kernel<<<dim3(64, 8), dim3(512), 0, stream>>>(obuf, woT, out, bo);
}

// Round 10
// 110.662 us; speedup vs baseline: 1.0433x; 1.0433x over previous
//
#include <hip/hip_runtime.h>
#include <stdint.h>

#define N_SEQ 2048
#define QKFV_COLS 2048

typedef __attribute__((ext_vector_type(8))) __bf16 bf16x8;
typedef __attribute__((ext_vector_type(4))) __bf16 bf16x4;
typedef __attribute__((ext_vector_type(4))) float f32x4;
typedef __attribute__((ext_vector_type(16))) float f32x16;

#if __has_builtin(__builtin_amdgcn_exp2f)
#define EXP2(x) __builtin_amdgcn_exp2f(x)
#else
#define EXP2(x) exp2f(x)
#endif

__device__ __forceinline__ f32x4 mfma16(bf16x8 a, bf16x8 b, f32x4 c) {
  return __builtin_amdgcn_mfma_f32_16x16x32_bf16(a, b, c, 0, 0, 0);
}
__device__ __forceinline__ f32x16 mfma32(bf16x8 a, bf16x8 b, f32x16 c) {
  return __builtin_amdgcn_mfma_f32_32x32x16_bf16(a, b, c, 0, 0, 0);
}

__device__ __forceinline__ void glds16(const void* g, void* l) {
  __builtin_amdgcn_global_load_lds(
      (__attribute__((address_space(1))) uint32_t*)(uintptr_t)g,
      (__attribute__((address_space(3))) uint32_t*)l, 16, 0, 0);
}

// ---------------- fused prep: cast x + 3 LDS-tiled transposes ----------------
__global__ __launch_bounds__(256) void prep_kernel(const float* __restrict__ x,
                                                   __bf16* __restrict__ xbf,
                                                   const float* __restrict__ wqk,
                                                   __bf16* __restrict__ wqT,
                                                   const float* __restrict__ wo,
                                                   __bf16* __restrict__ woT,
                                                   const float* __restrict__ wsc,
                                                   __bf16* __restrict__ wscT) {
  const int t = threadIdx.x;
  int bid = blockIdx.x;
  if (bid < 2048) {
    size_t i = (size_t)bid * 2048 + t * 8;
    const float* p = x + i;
    bf16x8 o;
#pragma unroll
    for (int j = 0; j < 8; ++j) o[j] = (__bf16)p[j];
    *(bf16x8*)(xbf + i) = o;
    return;
  }
  bid -= 2048;
  const float* in;
  __bf16* outp;
  int R, C, rt, ct;
  if (bid < 256) { in = wqk; outp = wqT; R = 512; C = 2048; rt = bid >> 5; ct = bid & 31; }
  else if (bid < 320) { int b2 = bid - 256; in = wo; outp = woT; R = 512; C = 512; rt = b2 >> 3; ct = b2 & 7; }
  else { int b2 = bid - 320; in = wsc; outp = wscT; R = 64; C = 2048; rt = 0; ct = b2; }
  __shared__ __bf16 tile[64][72];
  const int r0 = rt * 64, c0 = ct * 64;
  {
    const int r = t >> 2, cq = (t & 3) * 16;
    const float* src = in + (size_t)(r0 + r) * C + c0 + cq;
#pragma unroll
    for (int q = 0; q < 4; ++q) {
      f32x4 v = *(const f32x4*)(src + q * 4);
#pragma unroll
      for (int e = 0; e < 4; ++e) tile[r][cq + q * 4 + e] = (__bf16)v[e];
    }
  }
  __syncthreads();
  {
    const int c = t >> 2, rq = (t & 3) * 16;
    __bf16* dst = outp + (size_t)(c0 + c) * R + r0 + rq;
    bf16x8 o0, o1;
#pragma unroll
    for (int j = 0; j < 8; ++j) { o0[j] = tile[rq + j][c]; o1[j] = tile[rq + 8 + j][c]; }
    *(bf16x8*)dst = o0;
    *(bf16x8*)(dst + 8) = o1;
  }
}

// ---------------- gemm_qkfv: BM128 x BN256 x BK32, 8 waves, 2 blocks/CU ----------------
__global__ __launch_bounds__(512, 4) void gemm_qkfv_kernel(const __bf16* __restrict__ A,
                                                           const __bf16* __restrict__ Bt,
                                                           __bf16* __restrict__ C,
                                                           __bf16* __restrict__ fT,
                                                           __bf16* __restrict__ vT) {
  __shared__ alignas(16) __bf16 Ab[2][128 * 32];
  __shared__ alignas(16) __bf16 Bb[2][256 * 32];
  const int K = 512, N = 2048;
  const int t = threadIdx.x;
  const int w = t >> 6;
  const int lane = t & 63;
  const int l15 = lane & 15;
  const int q4 = lane >> 4;
  const int g4 = q4 * 4;
  const int wr = w >> 2, wc = w & 3;
  const int bid = blockIdx.x;
  const int n0 = (bid & 7) * 256;
  const int m0 = (bid >> 3) * 128;

  const __bf16* srcA;
  const __bf16* srcB[2];
  {
    int s = t, r = s >> 2, u = (s & 3) ^ (r & 3);
    srcA = A + (size_t)(m0 + r) * K + u * 8;
  }
#pragma unroll
  for (int c = 0; c < 2; ++c) {
    int s = c * 512 + t, r = s >> 2, u = (s & 3) ^ (r & 3);
    srcB[c] = Bt + (size_t)(n0 + r) * K + u * 8;
  }

  f32x4 acc[4][4];
#pragma unroll
  for (int m = 0; m < 4; ++m)
#pragma unroll
    for (int n = 0; n < 4; ++n) acc[m][n] = (f32x4){0.f, 0.f, 0.f, 0.f};

  glds16(srcA, &Ab[0][t * 8]);
  glds16(srcB[0], &Bb[0][t * 8]);
  glds16(srcB[1], &Bb[0][(512 + t) * 8]);

  for (int kt = 0; kt < 16; ++kt) {
    const int cur = kt & 1;
    asm volatile("s_waitcnt vmcnt(0)" ::: "memory");
    __builtin_amdgcn_s_barrier();
    if (kt < 15) {
      const int k0 = (kt + 1) * 32;
      glds16(srcA + k0, &Ab[cur ^ 1][t * 8]);
      glds16(srcB[0] + k0, &Bb[cur ^ 1][t * 8]);
      glds16(srcB[1] + k0, &Bb[cur ^ 1][(512 + t) * 8]);
    }
    bf16x8 af[4], bf[4];
#pragma unroll
    for (int m = 0; m < 4; ++m) {
      const int R = wr * 64 + m * 16 + l15;
      af[m] = *(const bf16x8*)&Ab[cur][R * 32 + ((q4 ^ (R & 3)) * 8)];
    }
#pragma unroll
    for (int n = 0; n < 4; ++n) {
      const int R = wc * 64 + n * 16 + l15;
      bf[n] = *(const bf16x8*)&Bb[cur][R * 32 + ((q4 ^ (R & 3)) * 8)];
    }
    __builtin_amdgcn_s_setprio(1);
#pragma unroll
    for (int m = 0; m < 4; ++m)
#pragma unroll
      for (int n = 0; n < 4; ++n) acc[m][n] = mfma16(af[m], bf[n], acc[m][n]);
    __builtin_amdgcn_s_setprio(0);
    __builtin_amdgcn_s_barrier();
  }

  if (n0 < 1024) {
#pragma unroll
    for (int m = 0; m < 4; ++m)
#pragma unroll
      for (int n = 0; n < 4; ++n) {
        const int col = n0 + wc * 64 + n * 16 + l15;
        const int row = m0 + wr * 64 + m * 16 + g4;
#pragma unroll
        for (int r = 0; r < 4; ++r)
          C[(size_t)(row + r) * N + col] = (__bf16)acc[m][n][r];
      }
  } else {
    __bf16* T = (n0 < 1536) ? fT : vT;
    const int cbase = (n0 < 1536) ? 1024 : 1536;
#pragma unroll
    for (int m = 0; m < 4; ++m)
#pragma unroll
      for (int n = 0; n < 4; ++n) {
        const int hc = n0 + wc * 64 + n * 16 + l15 - cbase;  // 0..511
        const int h = hc >> 6, d = hc & 63;
        const int row = m0 + wr * 64 + m * 16 + g4;
        const int b = row >> 11, nl = row & 2047;
        bf16x4 pk;
#pragma unroll
        for (int r = 0; r < 4; ++r) pk[r] = (__bf16)acc[m][n][r];
        *(bf16x4*)&T[(size_t)((b * 8 + h) * 64 + d) * 2048 + nl] = pk;
      }
  }
}

// ---------------- gemm_out: BM128 x BN64 x BK32, dbuf, XCD-aligned A reuse ----------------
// bid mapping: m = (bid&7) | (((bid>>3)&7)<<3), n = bid>>6  =>  xcd = bid%8 = m%8,
// so all 8 n-panels of one A row-block land on the same XCD (A panel L2-resident).
__global__ __launch_bounds__(512, 4) void gemm_out_kernel(const __bf16* __restrict__ A,
                                                          const __bf16* __restrict__ Bt,
                                                          float* __restrict__ out,
                                                          const float* __restrict__ bias) {
  __shared__ alignas(16) __bf16 Ab[2][128 * 32];
  __shared__ alignas(16) __bf16 Bb[2][64 * 32];
  const int K = 512, N = 512;
  const int t = threadIdx.x;
  const int w = t >> 6;
  const int lane = t & 63;
  const int l15 = lane & 15;
  const int q4 = lane >> 4;
  const int g4 = q4 * 4;
  const int wr = w >> 1, wc = w & 1;
  const int bid = blockIdx.x;
  const int m0 = (((bid & 7) | (((bid >> 3) & 7) << 3))) * 128;
  const int n0 = (bid >> 6) * 64;

  const __bf16* srcA;
  const __bf16* srcB;
  {
    int s = t, r = s >> 2, u = (s & 3) ^ (r & 3);
    srcA = A + (size_t)(m0 + r) * K + u * 8;
    srcB = Bt + (size_t)(n0 + (r & 63)) * K + u * 8;
  }

  f32x4 acc[2][2];
#pragma unroll
  for (int m = 0; m < 2; ++m)
#pragma unroll
    for (int n = 0; n < 2; ++n) acc[m][n] = (f32x4){0.f, 0.f, 0.f, 0.f};

  glds16(srcA, &Ab[0][t * 8]);
  if (t < 256) glds16(srcB, &Bb[0][t * 8]);

  for (int kt = 0; kt < 16; ++kt) {
    const int cur = kt & 1;
    asm volatile("s_waitcnt vmcnt(0)" ::: "memory");
    __builtin_amdgcn_s_barrier();
    if (kt < 15) {
      const int k0 = (kt + 1) * 32;
      glds16(srcA + k0, &Ab[cur ^ 1][t * 8]);
      if (t < 256) glds16(srcB + k0, &Bb[cur ^ 1][t * 8]);
    }
    bf16x8 af[2], bf[2];
#pragma unroll
    for (int m = 0; m < 2; ++m) {
      const int R = wr * 32 + m * 16 + l15;
      af[m] = *(const bf16x8*)&Ab[cur][R * 32 + ((q4 ^ (R & 3)) * 8)];
    }
#pragma unroll
    for (int n = 0; n < 2; ++n) {
      const int R = wc * 32 + n * 16 + l15;
      bf[n] = *(const bf16x8*)&Bb[cur][R * 32 + ((q4 ^ (R & 3)) * 8)];
    }
    __builtin_amdgcn_s_setprio(1);
#pragma unroll
    for (int m = 0; m < 2; ++m)
#pragma unroll
      for (int n = 0; n < 2; ++n) acc[m][n] = mfma16(af[m], bf[n], acc[m][n]);
    __builtin_amdgcn_s_setprio(0);
    __builtin_amdgcn_s_barrier();
  }

#pragma unroll
  for (int m = 0; m < 2; ++m)
#pragma unroll
    for (int n = 0; n < 2; ++n) {
      const int col = n0 + wc * 32 + n * 16 + l15;
      const float bv = bias[col];
      const int row = m0 + wr * 32 + m * 16 + g4;
#pragma unroll
      for (int r = 0; r < 4; ++r)
        out[(size_t)(row + r) * N + col] = acc[m][n][r] + bv;
    }
}

// ---------------- fvmm ----------------
__global__ __launch_bounds__(256) void fvmm_kernel(const __bf16* __restrict__ fT,
                                                   const __bf16* __restrict__ vT,
                                                   float* __restrict__ fvp) {
  __shared__ alignas(16) __bf16 As[2 * 8192];
  __shared__ alignas(16) __bf16 Bs[2 * 8192];
  const int t = threadIdx.x;
  const int w = t >> 6;
  const int lane = t & 63;
  const int l15 = lane & 15;
  const int q4 = lane >> 4;
  const int g4 = q4 * 4;
  const int sl = blockIdx.x;
  const int bh = blockIdx.y;
  const int k0 = sl * 256;
  const __bf16* A = fT + (size_t)bh * 131072 + k0;
  const __bf16* B = vT + (size_t)bh * 131072 + k0;

#pragma unroll
  for (int kt = 0; kt < 2; ++kt)
#pragma unroll
    for (int c = 0; c < 4; ++c) {
      int slot = c * 256 + t;
      int r = slot >> 4, u = (slot & 15) ^ (r & 7);
      glds16(A + (size_t)r * 2048 + kt * 128 + u * 8, &As[kt * 8192 + (c * 256 + w * 64) * 8]);
      glds16(B + (size_t)r * 2048 + kt * 128 + u * 8, &Bs[kt * 8192 + (c * 256 + w * 64) * 8]);
    }
  asm volatile("s_waitcnt vmcnt(0)" ::: "memory");
  __syncthreads();

  f32x4 acc[4];
#pragma unroll
  for (int nb = 0; nb < 4; ++nb) acc[nb] = (f32x4){0.f, 0.f, 0.f, 0.f};
  const int arow = w * 16 + l15;
#pragma unroll
  for (int ks = 0; ks < 8; ++ks) {
    const int kt = ks >> 2;
    const int ku = (ks & 3) * 4 + q4;
    bf16x8 a = *(const bf16x8*)&As[kt * 8192 + arow * 128 + ((ku ^ (arow & 7)) * 8)];
#pragma unroll
    for (int nb = 0; nb < 4; ++nb) {
      const int br = nb * 16 + l15;
      bf16x8 bb = *(const bf16x8*)&Bs[kt * 8192 + br * 128 + ((ku ^ (br & 7)) * 8)];
      acc[nb] = mfma16(a, bb, acc[nb]);
    }
  }
  float* dst = fvp + (size_t)(sl * 32 + bh) * 4096;
#pragma unroll
  for (int nb = 0; nb < 4; ++nb)
#pragma unroll
    for (int r = 0; r < 4; ++r)
      dst[(w * 16 + g4 + r) * 64 + nb * 16 + l15] = acc[nb][r];
}

// ---------------- pvmat2 ----------------
__global__ __launch_bounds__(256) void pvmat2_kernel(const float* __restrict__ fvp,
                                                     const __bf16* __restrict__ wscT,
                                                     const float* __restrict__ bsc,
                                                     __bf16* __restrict__ pvm) {
  __shared__ alignas(16) __bf16 fs[64 * 72];
  __shared__ alignas(16) __bf16 Ws[128 * 64];
  const int t = threadIdx.x;
  const int w = t >> 6;
  const int lane = t & 63;
  const int l15 = lane & 15;
  const int q4 = lane >> 4;
  const int g4 = q4 * 4;
  const int bh = blockIdx.y;
  const int j0 = blockIdx.x * 128;

#pragma unroll
  for (int c = 0; c < 4; ++c) {
    int slot = c * 256 + t;
    int r = slot >> 3, u = (slot & 7) ^ (r & 7);
    glds16(wscT + (size_t)(j0 + r) * 64 + u * 8, &Ws[(c * 256 + w * 64) * 8]);
  }
#pragma unroll
  for (int qq = 0; qq < 4; ++qq) {
    int idx = t * 16 + qq * 4;
    f32x4 s = (f32x4){0.f, 0.f, 0.f, 0.f};
#pragma unroll
    for (int sl = 0; sl < 8; ++sl)
      s += *(const f32x4*)&fvp[(size_t)(sl * 32 + bh) * 4096 + idx];
    bf16x4 pk;
#pragma unroll
    for (int e = 0; e < 4; ++e) pk[e] = (__bf16)s[e];
    *(bf16x4*)&fs[(idx >> 6) * 72 + (idx & 63)] = pk;
  }
  asm volatile("s_waitcnt vmcnt(0)" ::: "memory");
  __syncthreads();

  f32x4 acc[8];
#pragma unroll
  for (int nb = 0; nb < 8; ++nb) {
    float bv = bsc[j0 + nb * 16 + l15];
    acc[nb] = (f32x4){bv, bv, bv, bv};
  }
  const int arow = w * 16 + l15;
#pragma unroll
  for (int ks = 0; ks < 2; ++ks) {
    bf16x8 a = *(const bf16x8*)&fs[arow * 72 + ks * 32 + q4 * 8];
#pragma unroll
    for (int nb = 0; nb < 8; ++nb) {
      const int jr = nb * 16 + l15;
      bf16x8 bb = *(const bf16x8*)&Ws[jr * 64 + (((ks * 4 + q4) ^ (jr & 7)) * 8)];
      acc[nb] = mfma16(a, bb, acc[nb]);
    }
  }
  __bf16* dst = pvm + (size_t)bh * 131072 + (size_t)j0;
#pragma unroll
  for (int nb = 0; nb < 8; ++nb)
#pragma unroll
    for (int r = 0; r < 4; ++r)
      dst[(size_t)(w * 16 + g4 + r) * 2048 + nb * 16 + l15] = (__bf16)acc[nb][r];
}

// ---------------- flash attention, 8-wave j-split, no-max softmax (round-8 version) ----------------
__global__ __launch_bounds__(512, 4) void attn_kernel(const __bf16* __restrict__ qkfv,
                                                      const __bf16* __restrict__ pvm,
                                                      __bf16* __restrict__ obuf) {
  __shared__ alignas(16) char smem[65536];
  __bf16* Kb = (__bf16*)smem;             // [4][4096] : (g*2+buf)*4096
  __bf16* Vb = (__bf16*)(smem + 32768);   // [4][4096]
  const int t = threadIdx.x;
  const int w = t >> 6;        // 0..7
  const int g = w >> 2;        // j-group
  const int wq = w & 3;
  const int lane = t & 63;
  const int ln = lane & 31;
  const int hi = lane >> 5;
  const int p = blockIdx.x;
  const int bh = (p & 7) * 4 + ((p >> 3) & 3);
  const int iblk = p >> 5;
  const int b = bh >> 3, h = bh & 7;
  const int irow = iblk * 128 + wq * 32 + ln;
  const float K1 = 0.18033688f;  // 0.125 * log2(e), folded into Q
  const int swz = ln & 7;

  bf16x8 q[4];
  const __bf16* qrow = qkfv + (size_t)(b * N_SEQ + irow) * QKFV_COLS + h * 64 + hi * 8;
#pragma unroll
  for (int kf = 0; kf < 4; ++kf) {
    bf16x8 raw = *(const bf16x8*)(qrow + kf * 16);
#pragma unroll
    for (int e = 0; e < 8; ++e) q[kf][e] = (__bf16)((float)raw[e] * K1);
  }

  const int tg = t & 255;
  const __bf16* ksrc[2];
  const __bf16* vsrc[2];
#pragma unroll
  for (int it = 0; it < 2; ++it) {
    int s = it * 256 + tg;
    int r = s >> 3;
    int u = (s & 7) ^ (r & 7);
    ksrc[it] = qkfv + (size_t)(b * N_SEQ + g * 1024 + r) * QKFV_COLS + 512 + h * 64 + u * 8;
    vsrc[it] = pvm + ((size_t)bh * 64 + r) * 2048 + g * 1024 + u * 8;
  }

  auto stage = [&](int buf, int jt) {
#pragma unroll
    for (int it = 0; it < 2; ++it) {
      glds16(ksrc[it] + ((size_t)jt << 17), &Kb[(g * 2 + buf) * 4096 + (it * 256 + wq * 64) * 8]);
      glds16(vsrc[it] + jt * 64, &Vb[(g * 2 + buf) * 4096 + (it * 256 + wq * 64) * 8]);
    }
  };

  f32x16 o0, o1;
#pragma unroll
  for (int e = 0; e < 16; ++e) { o0[e] = 0.f; o1[e] = 0.f; }
  float lrl = 0.f;

  stage(0, 0);

  for (int jt = 0; jt < 16; ++jt) {
    asm volatile("s_waitcnt vmcnt(0)" ::: "memory");
    __builtin_amdgcn_s_barrier();
    if (jt < 15) stage((jt & 1) ^ 1, jt + 1);
    const int kc = (g * 2 + (jt & 1)) * 4096;

    f32x16 s0, s1;
#pragma unroll
    for (int e = 0; e < 16; ++e) { s0[e] = 0.f; s1[e] = 0.f; }
    __builtin_amdgcn_s_setprio(1);
#pragma unroll
    for (int kf = 0; kf < 4; ++kf) {
      bf16x8 k0 = *(const bf16x8*)&Kb[kc + (ln) * 64 + (((2 * kf + hi) ^ swz) * 8)];
      bf16x8 k1 = *(const bf16x8*)&Kb[kc + (32 + ln) * 64 + (((2 * kf + hi) ^ swz) * 8)];
      s0 = mfma32(k0, q[kf], s0);
      s1 = mfma32(k1, q[kf], s1);
    }
    __builtin_amdgcn_s_setprio(0);

#pragma unroll
    for (int e = 0; e < 16; ++e) s0[e] = EXP2(s0[e]);
#pragma unroll
    for (int e = 0; e < 16; ++e) s1[e] = EXP2(s1[e]);
    float a8[8];
#pragma unroll
    for (int e = 0; e < 8; ++e)
      a8[e] = (s0[e] + s0[e + 8]) + (s1[e] + s1[e + 8]);
    lrl += ((a8[0] + a8[4]) + (a8[1] + a8[5])) + ((a8[2] + a8[6]) + (a8[3] + a8[7]));

    bf16x8 pa[4];
#pragma unroll
    for (int kk = 0; kk < 4; ++kk) {
      const f32x16& sf = (kk < 2) ? s0 : s1;
      const int rb = (kk & 1) * 8;
      uint32_t a0, a1, b0, b1;
      asm("v_cvt_pk_bf16_f32 %0, %1, %2" : "=v"(a0) : "v"(sf[rb + 0]), "v"(sf[rb + 1]));
      asm("v_cvt_pk_bf16_f32 %0, %1, %2" : "=v"(a1) : "v"(sf[rb + 2]), "v"(sf[rb + 3]));
      asm("v_cvt_pk_bf16_f32 %0, %1, %2" : "=v"(b0) : "v"(sf[rb + 4]), "v"(sf[rb + 5]));
      asm("v_cvt_pk_bf16_f32 %0, %1, %2" : "=v"(b1) : "v"(sf[rb + 6]), "v"(sf[rb + 7]));
      asm("v_permlane32_swap_b32 %0, %1" : "+v"(a0), "+v"(b0));
      asm("v_permlane32_swap_b32 %0, %1" : "+v"(a1), "+v"(b1));
      union { uint32_t u[4]; bf16x8 v; } cv;
      cv.u[0] = a0; cv.u[1] = a1; cv.u[2] = b0; cv.u[3] = b1;
      pa[kk] = cv.v;
    }

    __builtin_amdgcn_s_setprio(1);
#pragma unroll
    for (int kk = 0; kk < 4; ++kk) {
      bf16x8 v0 = *(const bf16x8*)&Vb[kc + (ln) * 64 + (((2 * kk + hi) ^ swz) * 8)];
      bf16x8 v1 = *(const bf16x8*)&Vb[kc + (32 + ln) * 64 + (((2 * kk + hi) ^ swz) * 8)];
      o0 = mfma32(v0, pa[kk], o0);
      o1 = mfma32(v1, pa[kk], o1);
    }
    __builtin_amdgcn_s_setprio(0);
  }

  lrl += __shfl_xor(lrl, 32);

  __syncthreads();
  float* Om = (float*)smem;  // [4][64][33]
  if (w >= 4) {
    const int base = ((w - 4) * 64 + lane) * 33;
#pragma unroll
    for (int e = 0; e < 16; ++e) { Om[base + e] = o0[e]; Om[base + 16 + e] = o1[e]; }
    Om[base + 32] = lrl;
  }
  __syncthreads();
  if (w < 4) {
    const int base = (w * 64 + lane) * 33;
#pragma unroll
    for (int e = 0; e < 16; ++e) { o0[e] += Om[base + e]; o1[e] += Om[base + 16 + e]; }
    lrl += Om[base + 32];

    const float inv = 1.0f / lrl;
    const size_t orow = (size_t)(b * N_SEQ + irow) * 512 + h * 64;
#pragma unroll
    for (int df = 0; df < 2; ++df) {
      const f32x16& oo = df ? o1 : o0;
#pragma unroll
      for (int gg = 0; gg < 4; ++gg) {
        bf16x4 pk;
#pragma unroll
        for (int e = 0; e < 4; ++e) pk[e] = (__bf16)(oo[gg * 4 + e] * inv);
        *(bf16x4*)(obuf + orow + df * 32 + gg * 8 + hi * 4) = pk;
      }
    }
  }
}

extern "C" void kernel_launch(void* const* d_in, const int* in_sizes, int n_in,
                              void* d_out, int out_size, void* d_ws, size_t ws_size,
                              hipStream_t stream) {
  (void)in_sizes; (void)n_in; (void)out_size; (void)ws_size;
  const float* x   = (const float*)d_in[0];
  const float* wqk = (const float*)d_in[1];
  const float* wsc = (const float*)d_in[2];
  const float* bsc = (const float*)d_in[3];
  const float* wo  = (const float*)d_in[4];
  const float* bo  = (const float*)d_in[5];
  float* out = (float*)d_out;

  char* p = (char*)d_ws;
  __bf16* xbf  = (__bf16*)p;  p += (size_t)8192 * 512 * 2;   // dead after gemm_qkfv -> fvp
  __bf16* wqT  = (__bf16*)p;  p += (size_t)2048 * 512 * 2;
  __bf16* woT  = (__bf16*)p;  p += (size_t)512 * 512 * 2;
  __bf16* wscT = (__bf16*)p;  p += (size_t)2048 * 64 * 2;
  __bf16* qkfv = (__bf16*)p;  p += (size_t)8192 * 2048 * 2;  // only q/k halves used
  __bf16* pvm  = (__bf16*)p;  p += (size_t)32 * 64 * 2048 * 2;  // doubles as vT
  __bf16* obuf = (__bf16*)p;  p += (size_t)8192 * 512 * 2;      // doubles as fT
  float* fvp = (float*)xbf;
  __bf16* fT = obuf;
  __bf16* vT = pvm;

  prep_kernel<<<dim3(2400), dim3(256), 0, stream>>>(x, xbf, wqk, wqT, wo, woT, wsc, wscT);
  gemm_qkfv_kernel<<<dim3(512), dim3(512), 0, stream>>>(xbf, wqT, qkfv, fT, vT);
  fvmm_kernel<<<dim3(8, 32), dim3(256), 0, stream>>>(fT, vT, fvp);
  pvmat2_kernel<<<dim3(16, 32), dim3(256), 0, stream>>>(fvp, wscT, bsc, pvm);
  attn_kernel<<<dim3(512), dim3(512), 0, stream>>>(qkfv, pvm, obuf);
  gemm_out_kernel<<<dim3(512), dim3(512), 0, stream>>>(obuf, woT, out, bo);
}